// Round 4
// baseline (61869.019 us; speedup 1.0000x reference)
//
#include <hip/hip_runtime.h>
#include <stdint.h>

#define HH 640
#define BB 128
#define TT 512
#define VV 4097
#define G4 2560   // 4*HH
#define VP2 4608  // padded Wout width (256*18)
#define NB 256    // persistent blocks
#define P1B 160   // blocks doing P1/P2 GEMM

typedef float f32x4v __attribute__((ext_vector_type(4)));
typedef float f32x2v __attribute__((ext_vector_type(2)));

__device__ __forceinline__ float sigm(float x){ return 1.0f/(1.0f+expf(-x)); }

// monotonic packed key: larger logit wins; ties -> smaller v (jnp.argmax first-index)
__device__ __forceinline__ unsigned long long packkey(float f, unsigned v){
    unsigned u = __float_as_uint(f);
    unsigned m = (u & 0x80000000u) ? ~u : (u | 0x80000000u);
    return ((unsigned long long)m << 32) | (unsigned long long)(~v);
}

// transposed state addressing: [k>>2][b][k&3] as float index
__device__ __forceinline__ size_t taddr(int k, int b){
    return ((size_t)(k>>2)*BB + b)*4 + (k&3);
}

// ---------------- grid barrier (agent-scope) ----------------
__device__ __forceinline__ void gridbar(unsigned* cnt, unsigned* gen){
    __syncthreads();
    if (threadIdx.x == 0){
        unsigned g = __hip_atomic_load(gen, __ATOMIC_RELAXED, __HIP_MEMORY_SCOPE_AGENT);
        unsigned r = __hip_atomic_fetch_add(cnt, 1u, __ATOMIC_ACQ_REL, __HIP_MEMORY_SCOPE_AGENT);
        if (r == NB-1u){
            __hip_atomic_store(cnt, 0u, __ATOMIC_RELAXED, __HIP_MEMORY_SCOPE_AGENT);
            __hip_atomic_fetch_add(gen, 1u, __ATOMIC_ACQ_REL, __HIP_MEMORY_SCOPE_AGENT);
        } else {
            while (__hip_atomic_load(gen, __ATOMIC_RELAXED, __HIP_MEMORY_SCOPE_AGENT) == g)
                __builtin_amdgcn_s_sleep(2);
            (void)__hip_atomic_load(gen, __ATOMIC_ACQUIRE, __HIP_MEMORY_SCOPE_AGENT);
        }
    }
    __syncthreads();
}

// ---------------- init (transposed layout) ----------------
__global__ __launch_bounds__(256) void k_init3(const float* __restrict__ h0, const float* __restrict__ c0,
                       float* __restrict__ hs0, float* __restrict__ csT,
                       int* __restrict__ label, unsigned long long* __restrict__ slot8,
                       unsigned* __restrict__ bars){
    int i = blockIdx.x*256 + threadIdx.x;
    if (i < BB*HH){
        int b = i / HH, jj = i % HH;
        size_t o = taddr(jj, b);
        hs0[o] = h0[i]; csT[o] = c0[i];
    }
    if (i < BB) label[i] = 0;
    if (i < 8*BB) slot8[i] = 0ULL;
    if (i < 2) bars[i] = 0u;
}

// ---------------- one-time transposes ----------------
// gate-interleaved: WT[k][jj*4+g] = W[(g*HH+jj)*HH + k]
__global__ __launch_bounds__(256) void k_tr_gate(const float* __restrict__ W, float* __restrict__ WT){
    int idx = blockIdx.x*256 + threadIdx.x;   // 2560*160
    if (idx >= G4*160) return;
    int row = idx / 160, kq = idx % 160;
    int g = row / HH, jj = row % HH;
    float4 f = *reinterpret_cast<const float4*>(W + (size_t)row*HH + kq*4);
    WT[(size_t)(kq*4+0)*G4 + jj*4+g] = f.x;
    WT[(size_t)(kq*4+1)*G4 + jj*4+g] = f.y;
    WT[(size_t)(kq*4+2)*G4 + jj*4+g] = f.z;
    WT[(size_t)(kq*4+3)*G4 + jj*4+g] = f.w;
}
// WT[k][n] = W[n*HH+k], 640x640
__global__ __launch_bounds__(256) void k_tr640(const float* __restrict__ W, float* __restrict__ WT){
    int idx = blockIdx.x*256 + threadIdx.x;   // 640*160
    if (idx >= HH*160) return;
    int n = idx / 160, kq = idx % 160;
    float4 f = *reinterpret_cast<const float4*>(W + (size_t)n*HH + kq*4);
    WT[(size_t)(kq*4+0)*HH + n] = f.x;
    WT[(size_t)(kq*4+1)*HH + n] = f.y;
    WT[(size_t)(kq*4+2)*HH + n] = f.z;
    WT[(size_t)(kq*4+3)*HH + n] = f.w;
}
// WoutT2[k][v] padded to VP2, zero pad
__global__ __launch_bounds__(256) void k_tr_wout2(const float* __restrict__ W, float* __restrict__ WT){
    int idx = blockIdx.x*256 + threadIdx.x;   // VP2*160
    if (idx >= VP2*160) return;
    int v = idx / 160, kq = idx % 160;
    float4 f = make_float4(0.f,0.f,0.f,0.f);
    if (v < VV) f = *reinterpret_cast<const float4*>(W + (size_t)v*HH + kq*4);
    WT[(size_t)(kq*4+0)*VP2 + v] = f.x;
    WT[(size_t)(kq*4+1)*VP2 + v] = f.y;
    WT[(size_t)(kq*4+2)*VP2 + v] = f.z;
    WT[(size_t)(kq*4+3)*VP2 + v] = f.w;
}
__global__ __launch_bounds__(256) void k_boutpad2(const float* __restrict__ b_out, float* __restrict__ boutP){
    int v = blockIdx.x*256 + threadIdx.x;
    if (v < VP2) boutP[v] = (v < VV) ? b_out[v] : -1e30f;
}

// ---------------- emb_proj: [VV+1][2560] gate-interleaved; row VV = bias-only ----------------
// LDS-staged WihT slice, lane = v row, broadcast weights
__global__ __launch_bounds__(256) void k_embproj2(const float* __restrict__ emb,
                          const float* __restrict__ WihT,
                          const float* __restrict__ b_ih, const float* __restrict__ b_hh,
                          float* __restrict__ embproj){
    __shared__ float lw[640*16];
    int vt = blockIdx.x / 160, ut = blockIdx.x % 160;
    for (int i=threadIdx.x; i<640*16; i+=256)
        lw[i] = WihT[(size_t)(i>>4)*G4 + ut*16 + (i&15)];
    float bias[16];
    #pragma unroll
    for (int u=0;u<16;++u){
        int gu = ut*16+u, jj = gu>>2, g = gu&3;
        bias[u] = b_ih[g*HH+jj] + b_hh[g*HH+jj];
    }
    __syncthreads();
    int v = vt*256 + threadIdx.x;
    float acc[16];
    #pragma unroll
    for (int u=0;u<16;++u) acc[u]=0.f;
    if (v < VV){
        const float4* er = reinterpret_cast<const float4*>(emb + (size_t)v*HH);
        for (int k4=0;k4<160;++k4){
            float4 ev = er[k4];
            #pragma unroll
            for (int q=0;q<4;++q){
                float e = (q==0)?ev.x:(q==1)?ev.y:(q==2)?ev.z:ev.w;
                const f32x4v* wr = reinterpret_cast<const f32x4v*>(&lw[(k4*4+q)*16]);
                f32x4v w0=wr[0], w1=wr[1], w2=wr[2], w3=wr[3];
                acc[0]=fmaf(w0[0],e,acc[0]); acc[1]=fmaf(w0[1],e,acc[1]);
                acc[2]=fmaf(w0[2],e,acc[2]); acc[3]=fmaf(w0[3],e,acc[3]);
                acc[4]=fmaf(w1[0],e,acc[4]); acc[5]=fmaf(w1[1],e,acc[5]);
                acc[6]=fmaf(w1[2],e,acc[6]); acc[7]=fmaf(w1[3],e,acc[7]);
                acc[8]=fmaf(w2[0],e,acc[8]); acc[9]=fmaf(w2[1],e,acc[9]);
                acc[10]=fmaf(w2[2],e,acc[10]); acc[11]=fmaf(w2[3],e,acc[11]);
                acc[12]=fmaf(w3[0],e,acc[12]); acc[13]=fmaf(w3[1],e,acc[13]);
                acc[14]=fmaf(w3[2],e,acc[14]); acc[15]=fmaf(w3[3],e,acc[15]);
            }
        }
    }
    if (v <= VV){
        #pragma unroll
        for (int q=0;q<4;++q){
            float4 st = make_float4(acc[q*4+0]+bias[q*4+0], acc[q*4+1]+bias[q*4+1],
                                    acc[q*4+2]+bias[q*4+2], acc[q*4+3]+bias[q*4+3]);
            *reinterpret_cast<float4*>(embproj + (size_t)v*G4 + ut*16 + q*4) = st;
        }
    }
}

// ---------------- enc_proj precompute (layout [t][n][b]) ----------------
__global__ __launch_bounds__(128) void k_encprojT(const float* __restrict__ x,
                          const float* __restrict__ Wenc, const float* __restrict__ b_enc,
                          float* __restrict__ encprojT){
    int tile = (blockIdx.x & 7)*2560 + (blockIdx.x >> 3);
    int b   = tile / 160;
    int rem = tile % 160;
    int tt  = rem / 5;
    int nt2 = rem % 5;
    int lane = threadIdx.x & 63, w = threadIdx.x >> 6;
    int n = nt2*128 + w*64 + lane;
    float acc[16];
    #pragma unroll
    for (int i=0;i<16;i++) acc[i]=0.f;
    const float* wr = Wenc + (size_t)n*HH;
    for (int kc=0; kc<HH; kc+=16){
        float wv[16];
        #pragma unroll
        for (int q=0;q<4;q++){
            float4 f = *reinterpret_cast<const float4*>(wr + kc + q*4);
            wv[q*4+0]=f.x; wv[q*4+1]=f.y; wv[q*4+2]=f.z; wv[q*4+3]=f.w;
        }
        #pragma unroll
        for (int k=0;k<16;k++){
            const float* xp = x + (size_t)b*HH*TT + (size_t)(kc+k)*TT + tt*16;
            float ww = wv[k];
            #pragma unroll
            for (int ti=0; ti<16; ++ti) acc[ti] = fmaf(xp[ti], ww, acc[ti]);
        }
    }
    float be = b_enc[n];
    #pragma unroll
    for (int ti=0; ti<16; ++ti)
        encprojT[((size_t)(tt*16+ti)*HH + n)*BB + b] = acc[ti] + be;
}

// ================= persistent cooperative kernel =================
__global__ __launch_bounds__(256,1) void k_persist(
    const float* __restrict__ WhhT, const float* __restrict__ WpredT,
    const float* __restrict__ WoutT2, const float* __restrict__ embproj,
    const float* __restrict__ encprojT, const float* __restrict__ b_pred,
    const float* __restrict__ boutP2, const int* __restrict__ lens,
    float* hsA, float* hsBf, float* h1A, float* h1Bf,
    float* csT, float* c1T, float* jointT,
    int* label, unsigned long long* slot8,
    unsigned* barcnt, unsigned* bargen,
    float* dout)
{
    __shared__ float lds_whh[640*16];    // 40.96 KB
    __shared__ float lds_wpred[640*4];   // 10.24 KB
    __shared__ float lds_wout[640*20];   // 51.20 KB (18 used, 2 pad for align)
    __shared__ float lds_red[18*128];    //  9.22 KB

    const int tid = threadIdx.x;
    const int bid = blockIdx.x;
    const int b   = tid & 127;
    const int kh  = tid >> 7;

    // ---- stage weight slices into LDS (once) ----
    if (bid < P1B){
        for (int i=tid; i<640*16; i+=256){
            int k=i>>4, u=i&15;
            lds_whh[i] = WhhT[(size_t)k*G4 + bid*16 + u];
        }
        for (int i=tid; i<640*4; i+=256){
            int k=i>>2, u=i&3;
            lds_wpred[i] = WpredT[(size_t)k*HH + bid*4 + u];
        }
    }
    for (int i=tid; i<640*18; i+=256){
        int k=i/18, u=i-k*18;
        lds_wout[k*20+u] = WoutT2[(size_t)k*VP2 + bid*18 + u];
    }
    float bo[18];
    #pragma unroll
    for (int v=0;v<18;++v) bo[v] = boutP2[bid*18+v];
    float bp4[4] = {0.f,0.f,0.f,0.f};
    if (bid < P1B){
        #pragma unroll
        for (int j=0;j<4;++j) bp4[j] = b_pred[bid*4+j];
    }
    const int len_b = lens[b];
    __syncthreads();

    float* hsB2[2] = {hsA, hsBf};
    float* h1B2[2] = {h1A, h1Bf};

    for (int t=0; t<TT; ++t){
        const float* hsr = hsB2[t&1];
        float*       hsw = hsB2[(t+1)&1];
        const float* h1r = h1B2[(t+1)&1];
        float*       h1w = h1B2[t&1];

        // lazy-commit decision for step t-1 (per-thread, for its b)
        bool mask; int sel=0, kprev=0;
        if (t==0){ mask=true; sel=0; }
        else {
            unsigned long long key = slot8[b];
            #pragma unroll
            for (int q=1;q<8;++q){
                unsigned long long o = slot8[q*128+b];
                if (o>key) key=o;
            }
            int k = (int)(~(unsigned)key);
            int lab = label[b];
            mask = ((t-1) >= len_b) || (k==0);
            kprev=k; sel = mask ? lab : k;
        }

        // ================= P1: gates GEMM + LSTM nonlin =================
        if (bid < P1B){
            float a1[16];
            #pragma unroll
            for (int u=0;u<16;++u) a1[u]=0.f;
            const float4* hp = reinterpret_cast<const float4*>(mask ? hsr : h1r);
            const int k0 = kh*80;
            #pragma unroll 2
            for (int k4=k0; k4<k0+80; ++k4){
                float4 hv = hp[(size_t)k4*BB + b];
                #pragma unroll
                for (int q=0;q<4;++q){
                    float h = (q==0)?hv.x:(q==1)?hv.y:(q==2)?hv.z:hv.w;
                    const f32x4v* wr = reinterpret_cast<const f32x4v*>(&lds_whh[(k4*4+q)*16]);
                    f32x4v w0=wr[0], w1=wr[1], w2=wr[2], w3=wr[3];
                    a1[0]=fmaf(w0[0],h,a1[0]);  a1[1]=fmaf(w0[1],h,a1[1]);
                    a1[2]=fmaf(w0[2],h,a1[2]);  a1[3]=fmaf(w0[3],h,a1[3]);
                    a1[4]=fmaf(w1[0],h,a1[4]);  a1[5]=fmaf(w1[1],h,a1[5]);
                    a1[6]=fmaf(w1[2],h,a1[6]);  a1[7]=fmaf(w1[3],h,a1[7]);
                    a1[8]=fmaf(w2[0],h,a1[8]);  a1[9]=fmaf(w2[1],h,a1[9]);
                    a1[10]=fmaf(w2[2],h,a1[10]); a1[11]=fmaf(w2[3],h,a1[11]);
                    a1[12]=fmaf(w3[0],h,a1[12]); a1[13]=fmaf(w3[1],h,a1[13]);
                    a1[14]=fmaf(w3[2],h,a1[14]); a1[15]=fmaf(w3[3],h,a1[15]);
                }
            }
            if (kh==0){
                #pragma unroll
                for (int u=0;u<16;++u) lds_red[u*128+b] = a1[u];
            }
            __syncthreads();
            if (kh==1){
                int erow = (t==0) ? VV : sel;
                const float4* eb = reinterpret_cast<const float4*>(embproj + (size_t)erow*G4 + bid*16);
                const size_t so = (size_t)bid*BB + b;   // float4 index
                float4 ce4 = mask ? reinterpret_cast<const float4*>(csT)[so]
                                  : reinterpret_cast<const float4*>(c1T)[so];
                float4 he4 = mask ? reinterpret_cast<const float4*>(hsr)[so]
                                  : reinterpret_cast<const float4*>(h1r)[so];
                float cn[4], hn[4];
                const float* cep = &ce4.x;
                #pragma unroll
                for (int jl=0;jl<4;++jl){
                    float4 e = eb[jl];
                    float gi = lds_red[(jl*4+0)*128+b] + a1[jl*4+0] + e.x;
                    float gf = lds_red[(jl*4+1)*128+b] + a1[jl*4+1] + e.y;
                    float gg = lds_red[(jl*4+2)*128+b] + a1[jl*4+2] + e.z;
                    float go = lds_red[(jl*4+3)*128+b] + a1[jl*4+3] + e.w;
                    float ce = cep[jl];
                    float cv = sigm(gf)*ce + sigm(gi)*tanhf(gg);
                    cn[jl] = cv;
                    hn[jl] = sigm(go)*tanhf(cv);
                }
                reinterpret_cast<float4*>(csT)[so] = ce4;                 // committed through t-1
                reinterpret_cast<float4*>(c1T)[so] = make_float4(cn[0],cn[1],cn[2],cn[3]);
                reinterpret_cast<float4*>(hsw)[so] = he4;                 // committed through t-1
                reinterpret_cast<float4*>(h1w)[so] = make_float4(hn[0],hn[1],hn[2],hn[3]);
                if (bid==0){
                    if (t>0) dout[(size_t)b*TT + (t-1)] = mask ? 0.f : (float)kprev;
                    label[b] = sel;   // idempotent-select race-safe
                }
            }
        }
        gridbar(barcnt, bargen);

        // ================= P2: joint =================
        if (bid < P1B){
            float a2[4] = {0.f,0.f,0.f,0.f};
            const float4* hp2 = reinterpret_cast<const float4*>(h1w);
            const int k0 = kh*80;
            #pragma unroll 2
            for (int k4=k0; k4<k0+80; ++k4){
                float4 hv = hp2[(size_t)k4*BB + b];
                #pragma unroll
                for (int q=0;q<4;++q){
                    float h = (q==0)?hv.x:(q==1)?hv.y:(q==2)?hv.z:hv.w;
                    f32x4v wv = *reinterpret_cast<const f32x4v*>(&lds_wpred[(k4*4+q)*4]);
                    a2[0]=fmaf(wv[0],h,a2[0]); a2[1]=fmaf(wv[1],h,a2[1]);
                    a2[2]=fmaf(wv[2],h,a2[2]); a2[3]=fmaf(wv[3],h,a2[3]);
                }
            }
            if (kh==0){
                #pragma unroll
                for (int j=0;j<4;++j) lds_red[j*128+b] = a2[j];
            }
            __syncthreads();
            if (kh==1){
                float jn[4];
                #pragma unroll
                for (int j=0;j<4;++j){
                    float s = lds_red[j*128+b] + a2[j] + bp4[j]
                            + encprojT[((size_t)t*HH + bid*4+j)*BB + b];
                    jn[j] = fmaxf(s, 0.f);
                }
                reinterpret_cast<float4*>(jointT)[(size_t)bid*BB + b] =
                    make_float4(jn[0],jn[1],jn[2],jn[3]);
            }
        }
        if (bid==0 && kh==0){
            #pragma unroll
            for (int q=0;q<8;++q) slot8[q*128+b] = 0ULL;
        }
        gridbar(barcnt, bargen);

        // ================= P3: logits + argmax =================
        {
            float a3[18];
            #pragma unroll
            for (int v=0;v<18;++v) a3[v]=0.f;
            const float4* jp = reinterpret_cast<const float4*>(jointT);
            const int k0 = kh*80;
            #pragma unroll 2
            for (int k4=k0; k4<k0+80; ++k4){
                float4 jv = jp[(size_t)k4*BB + b];
                #pragma unroll
                for (int q=0;q<4;++q){
                    float h = (q==0)?jv.x:(q==1)?jv.y:(q==2)?jv.z:jv.w;
                    const float* base = &lds_wout[(k4*4+q)*20];
                    const f32x4v* wr = reinterpret_cast<const f32x4v*>(base);
                    f32x4v w0=wr[0], w1=wr[1], w2=wr[2], w3=wr[3];
                    f32x2v w4 = *reinterpret_cast<const f32x2v*>(base+16);
                    a3[0]=fmaf(w0[0],h,a3[0]);  a3[1]=fmaf(w0[1],h,a3[1]);
                    a3[2]=fmaf(w0[2],h,a3[2]);  a3[3]=fmaf(w0[3],h,a3[3]);
                    a3[4]=fmaf(w1[0],h,a3[4]);  a3[5]=fmaf(w1[1],h,a3[5]);
                    a3[6]=fmaf(w1[2],h,a3[6]);  a3[7]=fmaf(w1[3],h,a3[7]);
                    a3[8]=fmaf(w2[0],h,a3[8]);  a3[9]=fmaf(w2[1],h,a3[9]);
                    a3[10]=fmaf(w2[2],h,a3[10]); a3[11]=fmaf(w2[3],h,a3[11]);
                    a3[12]=fmaf(w3[0],h,a3[12]); a3[13]=fmaf(w3[1],h,a3[13]);
                    a3[14]=fmaf(w3[2],h,a3[14]); a3[15]=fmaf(w3[3],h,a3[15]);
                    a3[16]=fmaf(w4[0],h,a3[16]); a3[17]=fmaf(w4[1],h,a3[17]);
                }
            }
            if (kh==0){
                #pragma unroll
                for (int v=0;v<18;++v) lds_red[v*128+b] = a3[v];
            }
            __syncthreads();
            if (kh==1){
                unsigned long long key = 0ULL;
                #pragma unroll
                for (int v=0;v<18;++v){
                    float s = lds_red[v*128+b] + a3[v] + bo[v];
                    unsigned long long kk = packkey(s, (unsigned)(bid*18+v));
                    if (kk > key) key = kk;
                }
                atomicMax(&slot8[(bid&7)*128 + b], key);
            }
        }
        gridbar(barcnt, bargen);
    }

    // ================= final: emit t=511, hF, cF =================
    for (int idx = bid*256+tid; idx < BB*HH; idx += NB*256){
        int b2 = idx / HH, jj = idx - b2*HH;
        unsigned long long key = slot8[b2];
        #pragma unroll
        for (int q=1;q<8;++q){
            unsigned long long o = slot8[q*128+b2];
            if (o>key) key=o;
        }
        int k = (int)(~(unsigned)key);
        bool m = ((TT-1) >= lens[b2]) || (k==0);
        size_t o = taddr(jj, b2);
        dout[(size_t)BB*TT + idx]         = m ? hsB2[0][o] : h1B2[1][o];
        dout[(size_t)BB*TT + BB*HH + idx] = m ? csT[o] : c1T[o];
    }
    if (bid==0 && tid<BB){
        unsigned long long key = slot8[tid];
        #pragma unroll
        for (int q=1;q<8;++q){
            unsigned long long o = slot8[q*128+tid];
            if (o>key) key=o;
        }
        int k = (int)(~(unsigned)key);
        bool m = ((TT-1) >= lens[tid]) || (k==0);
        dout[(size_t)tid*TT + (TT-1)] = m ? 0.f : (float)k;
    }
}

// ================= fallback (small ws): R1 basic kernels =================
__global__ __launch_bounds__(256) void k_init(const float* __restrict__ h0, const float* __restrict__ c0,
                       float* __restrict__ hs0, float* __restrict__ cs,
                       int* __restrict__ label, unsigned long long* __restrict__ slot){
    int i = blockIdx.x*256 + threadIdx.x;
    if (i < BB*HH){ hs0[i] = h0[i]; cs[i] = c0[i]; }
    if (i < BB){ label[i] = 0; slot[i] = 0ULL; }
}

__global__ __launch_bounds__(256) void k_p1o(
    const float* __restrict__ Whh, const float* __restrict__ Wih,
    const float* __restrict__ embedding,
    const float* __restrict__ b_ih, const float* __restrict__ b_hh,
    const int* __restrict__ lens,
    const float* __restrict__ hs_r, float* __restrict__ hs_w,
    const float* __restrict__ h1_r, float* __restrict__ h1_w,
    float* c_state, float* c1, int* label,
    const unsigned long long* __restrict__ slot,
    float* __restrict__ out_emit, int t)
{
    int tile = (blockIdx.x & 7)*20 + (blockIdx.x >> 3);
    int jt = tile >> 4, bg = tile & 15;
    int lane = threadIdx.x & 63, w = threadIdx.x >> 6;
    int j = (jt<<6) + lane, b0 = bg<<3;

    bool mask[8]; int kprev[8]; int sel[8];
    #pragma unroll
    for (int bi=0; bi<8; ++bi){
        int b = b0+bi;
        if (t == 0){ mask[bi]=true; sel[bi]=0; kprev[bi]=0; }
        else {
            unsigned long long key = slot[b];
            int k = (int)(~(unsigned)key);
            int lab = label[b];
            bool m = ((t-1) >= lens[b]) || (k == 0);
            mask[bi]=m; kprev[bi]=k; sel[bi] = m ? lab : k;
        }
    }
    float acc[8];
    #pragma unroll
    for (int i=0;i<8;i++) acc[i]=0.f;
    const float* wrow  = Whh + (size_t)(w*HH + j)*HH;
    const float* wrow2 = Wih + (size_t)(w*HH + j)*HH;
    for (int kc=0; kc<HH; kc+=16){
        float wv[16], wv2[16];
        #pragma unroll
        for (int q=0;q<4;q++){
            float4 f = *reinterpret_cast<const float4*>(wrow + kc + q*4);
            wv[q*4+0]=f.x; wv[q*4+1]=f.y; wv[q*4+2]=f.z; wv[q*4+3]=f.w;
            float4 f2 = *reinterpret_cast<const float4*>(wrow2 + kc + q*4);
            wv2[q*4+0]=f2.x; wv2[q*4+1]=f2.y; wv2[q*4+2]=f2.z; wv2[q*4+3]=f2.w;
        }
        #pragma unroll
        for (int bi=0; bi<8; ++bi){
            int b = b0+bi;
            const float* hp0 = hs_r + (size_t)b*HH + kc;
            const float* hp1 = h1_r + (size_t)b*HH + kc;
            float a = acc[bi];
            if (mask[bi]){
                #pragma unroll
                for (int k=0;k<16;k++) a = fmaf(hp0[k], wv[k], a);
            } else {
                #pragma unroll
                for (int k=0;k<16;k++) a = fmaf(hp1[k], wv[k], a);
            }
            if (t > 0){
                const float* ep = embedding + (size_t)sel[bi]*HH + kc;
                #pragma unroll
                for (int k=0;k<16;k++) a = fmaf(ep[k], wv2[k], a);
            }
            acc[bi] = a;
        }
    }
    __shared__ float xch[8][4][64];
    #pragma unroll
    for (int bi=0; bi<8; ++bi)
        xch[bi][w][lane] = acc[bi] + b_ih[w*HH + j] + b_hh[w*HH + j];
    __syncthreads();
    #pragma unroll
    for (int r=0; r<2; ++r){
        int bi = (w<<1) + r;
        int b  = b0 + bi;
        size_t o = (size_t)b*HH + j;
        float gi = xch[bi][0][lane], gf = xch[bi][1][lane];
        float gg = xch[bi][2][lane], go = xch[bi][3][lane];
        float ce = mask[bi] ? c_state[o] : c1[o];
        float c2 = sigm(gf)*ce + sigm(gi)*tanhf(gg);
        float h2 = sigm(go)*tanhf(c2);
        float he = mask[bi] ? hs_r[o] : h1_r[o];
        c_state[o] = ce; c1[o] = c2; hs_w[o] = he; h1_w[o] = h2;
    }
    if (jt == 0 && t > 0 && threadIdx.x < 8){
        int bi = threadIdx.x; int b = b0 + bi;
        out_emit[(size_t)b*TT + (t-1)] = mask[bi] ? 0.0f : (float)kprev[bi];
        label[b] = sel[bi];
    }
}

__global__ __launch_bounds__(128) void k_p2o(
    const float* __restrict__ Wpred, const float* __restrict__ Wenc,
    const float* __restrict__ x, const float* __restrict__ b_enc,
    const float* __restrict__ b_pred, const float* __restrict__ h1,
    float* __restrict__ joint, unsigned long long* __restrict__ slot, int t)
{
    int tile = (blockIdx.x & 7)*20 + (blockIdx.x >> 3);
    int nt = tile / 32, bg = tile % 32;
    int lane = threadIdx.x & 63, w = threadIdx.x >> 6;
    int n = nt*128 + w*64 + lane, b0 = bg*4;
    float acc[4] = {0.f,0.f,0.f,0.f};
    const float* wr  = Wpred + (size_t)n*HH;
    const float* wr2 = Wenc  + (size_t)n*HH;
    for (int kc=0; kc<HH; kc+=16){
        float wv[16], wv2[16];
        #pragma unroll
        for (int q=0;q<4;q++){
            float4 f = *reinterpret_cast<const float4*>(wr + kc + q*4);
            wv[q*4+0]=f.x; wv[q*4+1]=f.y; wv[q*4+2]=f.z; wv[q*4+3]=f.w;
            float4 f2 = *reinterpret_cast<const float4*>(wr2 + kc + q*4);
            wv2[q*4+0]=f2.x; wv2[q*4+1]=f2.y; wv2[q*4+2]=f2.z; wv2[q*4+3]=f2.w;
        }
        #pragma unroll
        for (int bi=0; bi<4; ++bi){
            int b = b0+bi;
            const float* hp = h1 + (size_t)b*HH + kc;
            float a = acc[bi];
            #pragma unroll
            for (int k=0;k<16;k++) a = fmaf(hp[k], wv[k], a);
            const float* xp = x + (size_t)b*HH*TT + (size_t)kc*TT + t;
            #pragma unroll
            for (int k=0;k<16;k++) a = fmaf(xp[(size_t)k*TT], wv2[k], a);
            acc[bi] = a;
        }
    }
    #pragma unroll
    for (int bi=0; bi<4; ++bi){
        int b = b0+bi;
        joint[(size_t)b*HH + n] = fmaxf(acc[bi] + b_pred[n] + b_enc[n], 0.0f);
    }
    if (tile == 0) slot[threadIdx.x] = 0ULL;
}

__global__ __launch_bounds__(256) void k_p3o(
    const float* __restrict__ Wout, const float* __restrict__ b_out,
    const float* __restrict__ joint, unsigned long long* __restrict__ slot)
{
    int tile = (blockIdx.x & 7)*34 + (blockIdx.x >> 3);
    int vt = tile >> 4, bg = tile & 15;
    int lane = threadIdx.x & 63, w = threadIdx.x >> 6;
    int v = vt*256 + w*64 + lane;
    bool valid = v < VV;
    int vv = valid ? v : (VV-1);
    int b0 = bg*8;
    float acc[8];
    #pragma unroll
    for (int i=0;i<8;i++) acc[i]=0.f;
    const float* wr = Wout + (size_t)vv*HH;
    for (int kc=0; kc<HH; kc+=16){
        float wv[16];
        #pragma unroll
        for (int q=0;q<4;q++){
            float4 f = *reinterpret_cast<const float4*>(wr + kc + q*4);
            wv[q*4+0]=f.x; wv[q*4+1]=f.y; wv[q*4+2]=f.z; wv[q*4+3]=f.w;
        }
        #pragma unroll
        for (int bi=0; bi<8; ++bi){
            int b = b0+bi;
            const float* jp = joint + (size_t)b*HH + kc;
            float a = acc[bi];
            #pragma unroll
            for (int k=0;k<16;k++) a = fmaf(jp[k], wv[k], a);
            acc[bi] = a;
        }
    }
    float bofl = b_out[vv];
    __shared__ unsigned long long redo[4][8];
    #pragma unroll
    for (int bi=0; bi<8; ++bi){
        unsigned long long key = valid ? packkey(acc[bi] + bofl, (unsigned)v) : 0ULL;
        #pragma unroll
        for (int off=32; off>0; off>>=1){
            unsigned long long o = __shfl_xor(key, off, 64);
            if (o > key) key = o;
        }
        if (lane == 0) redo[w][bi] = key;
    }
    __syncthreads();
    if (threadIdx.x < 8){
        int bi = threadIdx.x;
        unsigned long long m = redo[0][bi];
        #pragma unroll
        for (int q=1;q<4;q++) if (redo[q][bi] > m) m = redo[q][bi];
        atomicMax(&slot[b0+bi], m);
    }
}

__global__ __launch_bounds__(256) void k_finalo(const int* __restrict__ lens,
                        const unsigned long long* __restrict__ slot,
                        const float* __restrict__ hs_r, const float* __restrict__ h1_r,
                        const float* __restrict__ cs,  const float* __restrict__ c1,
                        float* __restrict__ dout)
{
    int i = blockIdx.x*256 + threadIdx.x;
    if (i >= BB*HH) return;
    int b = i / HH;
    unsigned long long key = slot[b];
    int k = (int)(~(unsigned)key);
    bool m = ((TT-1) >= lens[b]) || (k == 0);
    dout[BB*TT + i]         = m ? hs_r[i] : h1_r[i];
    dout[BB*TT + BB*HH + i] = m ? cs[i]   : c1[i];
    if (i < BB){
        unsigned long long key2 = slot[i];
        int k2 = (int)(~(unsigned)key2);
        bool mm = ((TT-1) >= lens[i]) || (k2 == 0);
        dout[(size_t)i*TT + (TT-1)] = mm ? 0.0f : (float)k2;
    }
}

extern "C" void kernel_launch(void* const* d_in, const int* in_sizes, int n_in,
                              void* d_out, int out_size, void* d_ws, size_t ws_size,
                              hipStream_t stream)
{
    const float* x     = (const float*)d_in[0];
    const int*   lens  = (const int*)  d_in[1];
    const float* emb   = (const float*)d_in[2];
    const float* Wih   = (const float*)d_in[3];
    const float* Whh   = (const float*)d_in[4];
    const float* bih   = (const float*)d_in[5];
    const float* bhh   = (const float*)d_in[6];
    const float* Wenc  = (const float*)d_in[7];
    const float* benc  = (const float*)d_in[8];
    const float* Wpred = (const float*)d_in[9];
    const float* bpred = (const float*)d_in[10];
    const float* Wout  = (const float*)d_in[11];
    const float* bout  = (const float*)d_in[12];
    const float* h0    = (const float*)d_in[13];
    const float* c0    = (const float*)d_in[14];
    float* out = (float*)d_out;
    (void)in_sizes; (void)n_in; (void)out_size;

    char* ws = (char*)d_ws;
    size_t off = 0;
    auto alloc = [&](size_t bytes) -> void* {
        void* p = ws + off; off += (bytes + 255) & ~(size_t)255; return p;
    };
    const size_t BH = (size_t)BB*HH*sizeof(float);
    float* hs0  = (float*)alloc(BH);
    float* hs1  = (float*)alloc(BH);
    float* h1b0 = (float*)alloc(BH);
    float* h1b1 = (float*)alloc(BH);
    float* cs   = (float*)alloc(BH);
    float* c1   = (float*)alloc(BH);
    float* joint= (float*)alloc(BH);
    int* label  = (int*)alloc(BB*sizeof(int));
    unsigned long long* slot8 = (unsigned long long*)alloc(8*BB*sizeof(unsigned long long));
    unsigned* bars = (unsigned*)alloc(2*sizeof(unsigned));

    size_t need = off
        + (((size_t)HH*G4*sizeof(float) + 255) & ~(size_t)255)   // WhhT
        + (((size_t)HH*G4*sizeof(float) + 255) & ~(size_t)255)   // WihT
        + (((size_t)HH*HH*sizeof(float) + 255) & ~(size_t)255)   // WpredT
        + (((size_t)HH*VP2*sizeof(float) + 255) & ~(size_t)255)  // WoutT2
        + (((size_t)VP2*sizeof(float) + 255) & ~(size_t)255)     // boutP2
        + (((size_t)(VV+1)*G4*sizeof(float) + 255) & ~(size_t)255)  // embproj
        + (((size_t)TT*BB*HH*sizeof(float) + 255) & ~(size_t)255); // encprojT

    if (ws_size >= need){
        float* WhhT   = (float*)alloc((size_t)HH*G4*sizeof(float));
        float* WihT   = (float*)alloc((size_t)HH*G4*sizeof(float));
        float* WpredT = (float*)alloc((size_t)HH*HH*sizeof(float));
        float* WoutT2 = (float*)alloc((size_t)HH*VP2*sizeof(float));
        float* boutP2 = (float*)alloc((size_t)VP2*sizeof(float));
        float* embproj= (float*)alloc((size_t)(VV+1)*G4*sizeof(float));
        float* encprojT=(float*)alloc((size_t)TT*BB*HH*sizeof(float));

        k_init3<<<(BB*HH+255)/256, 256, 0, stream>>>(h0, c0, hs0, cs, label, slot8, bars);
        k_tr_gate<<<(G4*160+255)/256, 256, 0, stream>>>(Whh, WhhT);
        k_tr_gate<<<(G4*160+255)/256, 256, 0, stream>>>(Wih, WihT);
        k_tr640 <<<(HH*160+255)/256, 256, 0, stream>>>(Wpred, WpredT);
        k_tr_wout2<<<(VP2*160+255)/256, 256, 0, stream>>>(Wout, WoutT2);
        k_boutpad2<<<(VP2+255)/256, 256, 0, stream>>>(bout, boutP2);
        k_embproj2<<<17*160, 256, 0, stream>>>(emb, WihT, bih, bhh, embproj);
        k_encprojT<<<20480, 128, 0, stream>>>(x, Wenc, benc, encprojT);

        const float* a0 = WhhT;   const float* a1 = WpredT;
        const float* a2 = WoutT2; const float* a3 = embproj;
        const float* a4 = encprojT; const float* a5 = bpred;
        const float* a6 = boutP2; const int*   a7 = lens;
        float* a8 = hs0;  float* a9 = hs1;
        float* a10 = h1b0; float* a11 = h1b1;
        float* a12 = cs;  float* a13 = c1; float* a14 = joint;
        int* a15 = label; unsigned long long* a16 = slot8;
        unsigned* a17 = bars; unsigned* a18 = bars + 1;
        float* a19 = out;
        void* args[] = {&a0,&a1,&a2,&a3,&a4,&a5,&a6,&a7,&a8,&a9,&a10,&a11,
                        &a12,&a13,&a14,&a15,&a16,&a17,&a18,&a19};
        hipLaunchCooperativeKernel((const void*)k_persist, dim3(NB), dim3(256),
                                   args, 0, stream);
        return;
    }

    // -------- fallback: basic per-step path (small ws) --------
    unsigned long long* slot = slot8;
    k_init<<<(BB*HH+255)/256, 256, 0, stream>>>(h0, c0, hs0, cs, label, slot);
    float* hsbuf[2] = {hs0, hs1};
    float* h1buf[2] = {h1b0, h1b1};
    for (int t = 0; t < TT; ++t){
        const float* hsr = hsbuf[t & 1];
        float*       hsw = hsbuf[(t+1) & 1];
        const float* h1r = h1buf[(t+1) & 1];
        float*       h1w = h1buf[t & 1];
        k_p1o<<<160, 256, 0, stream>>>(Whh, Wih, emb, bih, bhh, lens,
                                       hsr, hsw, h1r, h1w, cs, c1, label, slot, out, t);
        k_p2o<<<160, 128, 0, stream>>>(Wpred, Wenc, x, benc, bpred, h1w, joint, slot, t);
        k_p3o<<<272, 256, 0, stream>>>(Wout, bout, joint, slot);
    }
    k_finalo<<<(BB*HH+255)/256, 256, 0, stream>>>(lens, slot, hsbuf[0], h1buf[1], cs, c1, out);
}

// Round 5
// 33088.837 us; speedup vs baseline: 1.8698x; 1.8698x over previous
//
#include <hip/hip_runtime.h>
#include <stdint.h>

#define HH 640
#define BB 128
#define TT 512
#define VV 4097
#define G4 2560   // 4*HH
#define VP3 4104  // padded Wout width (216*19)
#define VE  4112  // padded embT cols

typedef float f32x4v __attribute__((ext_vector_type(4)));

__device__ __forceinline__ float sigm(float x){ return 1.0f/(1.0f+expf(-x)); }

// monotonic packed key: larger logit wins; ties -> smaller v (jnp.argmax first-index)
__device__ __forceinline__ unsigned long long packkey(float f, unsigned v){
    unsigned u = __float_as_uint(f);
    unsigned m = (u & 0x80000000u) ? ~u : (u | 0x80000000u);
    return ((unsigned long long)m << 32) | (unsigned long long)(~v);
}
__device__ __forceinline__ int xcd_tile(int bid, int per){ return (bid & 7)*per + (bid >> 3); }
// transposed state addressing: [k>>2][b][k&3]
__device__ __forceinline__ size_t taddr(int k, int b){
    return ((size_t)(k>>2)*BB + b)*4 + (k&3);
}

// ---------------- init (transposed state) ----------------
__global__ __launch_bounds__(256) void k_init3(const float* __restrict__ h0, const float* __restrict__ c0,
                       float* __restrict__ hs0, float* __restrict__ csT,
                       int* __restrict__ label, unsigned long long* __restrict__ slot8){
    int i = blockIdx.x*256 + threadIdx.x;
    if (i < BB*HH){
        int b = i / HH, jj = i % HH;
        size_t o = taddr(jj, b);
        hs0[o] = h0[i]; csT[o] = c0[i];
    }
    if (i < BB) label[i] = 0;
    if (i < 8*BB) slot8[i] = 0ULL;
}

// ---------------- one-time transposes ----------------
__global__ __launch_bounds__(256) void k_tr_gate(const float* __restrict__ W, float* __restrict__ WT){
    int idx = blockIdx.x*256 + threadIdx.x;   // G4*160
    if (idx >= G4*160) return;
    int row = idx / 160, kq = idx % 160;
    int g = row / HH, jj = row % HH;
    float4 f = *reinterpret_cast<const float4*>(W + (size_t)row*HH + kq*4);
    WT[(size_t)(kq*4+0)*G4 + jj*4+g] = f.x;
    WT[(size_t)(kq*4+1)*G4 + jj*4+g] = f.y;
    WT[(size_t)(kq*4+2)*G4 + jj*4+g] = f.z;
    WT[(size_t)(kq*4+3)*G4 + jj*4+g] = f.w;
}
__global__ __launch_bounds__(256) void k_tr640(const float* __restrict__ W, float* __restrict__ WT){
    int idx = blockIdx.x*256 + threadIdx.x;   // HH*160
    if (idx >= HH*160) return;
    int n = idx / 160, kq = idx % 160;
    float4 f = *reinterpret_cast<const float4*>(W + (size_t)n*HH + kq*4);
    WT[(size_t)(kq*4+0)*HH + n] = f.x;
    WT[(size_t)(kq*4+1)*HH + n] = f.y;
    WT[(size_t)(kq*4+2)*HH + n] = f.z;
    WT[(size_t)(kq*4+3)*HH + n] = f.w;
}
__global__ __launch_bounds__(256) void k_tr_wout3(const float* __restrict__ W, float* __restrict__ WT){
    int idx = blockIdx.x*256 + threadIdx.x;   // VP3*160
    if (idx >= VP3*160) return;
    int v = idx / 160, kq = idx % 160;
    float4 f = make_float4(0.f,0.f,0.f,0.f);
    if (v < VV) f = *reinterpret_cast<const float4*>(W + (size_t)v*HH + kq*4);
    WT[(size_t)(kq*4+0)*VP3 + v] = f.x;
    WT[(size_t)(kq*4+1)*VP3 + v] = f.y;
    WT[(size_t)(kq*4+2)*VP3 + v] = f.z;
    WT[(size_t)(kq*4+3)*VP3 + v] = f.w;
}
__global__ __launch_bounds__(256) void k_boutpad3(const float* __restrict__ b_out, float* __restrict__ boutP){
    int v = blockIdx.x*256 + threadIdx.x;
    if (v < VP3) boutP[v] = (v < VV) ? b_out[v] : -1e30f;
}
// emb -> embT[k][v], coalesced writes (lanes = v)
__global__ __launch_bounds__(256) void k_tr_embT(const float* __restrict__ emb, float* __restrict__ embT){
    int idx = blockIdx.x*256 + threadIdx.x;   // 160*VE
    if (idx >= 160*VE) return;
    int kq = idx / VE, v = idx % VE;
    float4 f = make_float4(0.f,0.f,0.f,0.f);
    if (v < VV) f = *reinterpret_cast<const float4*>(emb + (size_t)v*HH + kq*4);
    embT[(size_t)(kq*4+0)*VE + v] = f.x;
    embT[(size_t)(kq*4+1)*VE + v] = f.y;
    embT[(size_t)(kq*4+2)*VE + v] = f.z;
    embT[(size_t)(kq*4+3)*VE + v] = f.w;
}

// ---------------- emb_proj: [VV+1][2560] gate-interleaved; row VV = bias-only ----------------
__global__ __launch_bounds__(256) void k_embproj3(const float* __restrict__ embT,
                          const float* __restrict__ WihT,
                          const float* __restrict__ b_ih, const float* __restrict__ b_hh,
                          float* __restrict__ embproj){
    __shared__ float lwv[HH*16];
    int vt = blockIdx.x / 160, ut = blockIdx.x % 160;
    for (int i=threadIdx.x; i<HH*16; i+=256)
        lwv[i] = WihT[(size_t)(i>>4)*G4 + ut*16 + (i&15)];
    float bias[16];
    #pragma unroll
    for (int u=0;u<16;++u){
        int gu = ut*16+u, jj = gu>>2, g = gu&3;
        bias[u] = b_ih[g*HH+jj] + b_hh[g*HH+jj];
    }
    __syncthreads();
    int v = vt*256 + threadIdx.x;
    float acc[16];
    #pragma unroll
    for (int u=0;u<16;++u) acc[u]=0.f;
    if (v < VV){
        #pragma unroll 2
        for (int k=0;k<HH;++k){
            float e = embT[(size_t)k*VE + v];
            const f32x4v* wr = reinterpret_cast<const f32x4v*>(&lwv[k*16]);
            #pragma unroll
            for (int g=0; g<4; ++g){
                f32x4v w = wr[g];
                #pragma unroll
                for (int ee=0; ee<4; ++ee) acc[g*4+ee] = fmaf(w[ee], e, acc[g*4+ee]);
            }
        }
    }
    if (v <= VV){
        #pragma unroll
        for (int q=0;q<4;++q){
            float4 st = make_float4(acc[q*4+0]+bias[q*4+0], acc[q*4+1]+bias[q*4+1],
                                    acc[q*4+2]+bias[q*4+2], acc[q*4+3]+bias[q*4+3]);
            *reinterpret_cast<float4*>(embproj + (size_t)v*G4 + ut*16 + q*4) = st;
        }
    }
}

// ---------------- enc_proj precompute (coalesced WencT reads), layout [t][n][b] ----------------
__global__ __launch_bounds__(128) void k_encprojT2(const float* __restrict__ x,
                          const float* __restrict__ WencT, const float* __restrict__ b_enc,
                          float* __restrict__ encprojT){
    int tile = (blockIdx.x & 7)*2560 + (blockIdx.x >> 3);
    int b   = tile / 160;
    int rem = tile % 160;
    int tt  = rem / 5;
    int nt2 = rem % 5;
    int n = nt2*128 + threadIdx.x;
    float acc[16];
    #pragma unroll
    for (int i=0;i<16;i++) acc[i]=0.f;
    const float* xb = x + (size_t)b*HH*TT + tt*16;
    #pragma unroll 4
    for (int k=0;k<HH;++k){
        float wv = WencT[(size_t)k*HH + n];
        const float4* xp = reinterpret_cast<const float4*>(xb + (size_t)k*TT);
        float4 x0=xp[0], x1=xp[1], x2=xp[2], x3=xp[3];
        acc[0]=fmaf(x0.x,wv,acc[0]);  acc[1]=fmaf(x0.y,wv,acc[1]);
        acc[2]=fmaf(x0.z,wv,acc[2]);  acc[3]=fmaf(x0.w,wv,acc[3]);
        acc[4]=fmaf(x1.x,wv,acc[4]);  acc[5]=fmaf(x1.y,wv,acc[5]);
        acc[6]=fmaf(x1.z,wv,acc[6]);  acc[7]=fmaf(x1.w,wv,acc[7]);
        acc[8]=fmaf(x2.x,wv,acc[8]);  acc[9]=fmaf(x2.y,wv,acc[9]);
        acc[10]=fmaf(x2.z,wv,acc[10]); acc[11]=fmaf(x2.w,wv,acc[11]);
        acc[12]=fmaf(x3.x,wv,acc[12]); acc[13]=fmaf(x3.y,wv,acc[13]);
        acc[14]=fmaf(x3.z,wv,acc[14]); acc[15]=fmaf(x3.w,wv,acc[15]);
    }
    float be = b_enc[n];
    #pragma unroll
    for (int ti=0; ti<16; ++ti)
        encprojT[((size_t)(tt*16+ti)*HH + n)*BB + b] = acc[ti] + be;
}

// ================= per-step kernels (LDS weights, 4-way K-split) =================

// ---- A: gates GEMM + LSTM nonlin + lazy commit of t-1 ----
__global__ __launch_bounds__(512) void kA(
    const float* __restrict__ WhhT, const float* __restrict__ embproj,
    const int* __restrict__ lens,
    const float* __restrict__ hsrT, float* __restrict__ hswT,
    const float* __restrict__ h1rT, float* __restrict__ h1wT,
    float* __restrict__ csT, float* __restrict__ c1T,
    int* __restrict__ label, const unsigned long long* __restrict__ slot8,
    float* __restrict__ out_emit, int t)
{
    __shared__ float lw[HH*16];        // 41 KB
    __shared__ float red[3*16*128];    // 24.6 KB
    const int bid = xcd_tile(blockIdx.x, 20);   // 160 blocks, 16 gate-units each
    const int tid = threadIdx.x;
    const int b = tid & 127, kh = tid >> 7;
    const int u0 = bid*16;

    for (int i=tid; i<HH*16; i+=512)
        lw[i] = WhhT[(size_t)(i>>4)*G4 + u0 + (i&15)];

    bool mask; int sel=0, kprev=0;
    if (t==0){ mask=true; sel=0; }
    else{
        unsigned long long key = slot8[b];
        #pragma unroll
        for (int q=1;q<8;++q){ unsigned long long o=slot8[q*128+b]; if(o>key)key=o; }
        int k = (int)(~(unsigned)key);
        int lab = label[b];
        mask = ((t-1) >= lens[b]) || (k==0);
        kprev = k; sel = mask ? lab : k;
    }
    __syncthreads();

    const float4* hp = reinterpret_cast<const float4*>(mask ? hsrT : h1rT);
    float a1[16];
    #pragma unroll
    for (int u=0;u<16;++u) a1[u]=0.f;
    const int k0 = kh*40;
    #pragma unroll 2
    for (int k4=k0; k4<k0+40; ++k4){
        float4 hv = hp[(size_t)k4*BB + b];
        #pragma unroll
        for (int q=0;q<4;++q){
            float h = (q==0)?hv.x:(q==1)?hv.y:(q==2)?hv.z:hv.w;
            const f32x4v* wr = reinterpret_cast<const f32x4v*>(&lw[(k4*4+q)*16]);
            #pragma unroll
            for (int g=0; g<4; ++g){
                f32x4v w = wr[g];
                #pragma unroll
                for (int ee=0; ee<4; ++ee) a1[g*4+ee] = fmaf(w[ee], h, a1[g*4+ee]);
            }
        }
    }
    if (kh > 0){
        #pragma unroll
        for (int u=0;u<16;++u) red[((kh-1)*16+u)*128 + b] = a1[u];
    }
    __syncthreads();
    if (kh == 0){
        int erow = (t==0) ? VV : sel;
        const float4* eb = reinterpret_cast<const float4*>(embproj + (size_t)erow*G4 + u0);
        const size_t g4 = (size_t)bid*BB + b;   // float4 granule (units bid*4..+3)
        float4 ce4 = mask ? reinterpret_cast<const float4*>(csT)[g4]
                          : reinterpret_cast<const float4*>(c1T)[g4];
        float4 he4 = mask ? reinterpret_cast<const float4*>(hsrT)[g4]
                          : reinterpret_cast<const float4*>(h1rT)[g4];
        float cn[4], hn[4];
        const float* cep = &ce4.x;
        #pragma unroll
        for (int jl=0; jl<4; ++jl){
            float4 e = eb[jl];
            float gi = a1[jl*4+0] + red[(jl*4+0)*128+b] + red[(16+jl*4+0)*128+b] + red[(32+jl*4+0)*128+b] + e.x;
            float gf = a1[jl*4+1] + red[(jl*4+1)*128+b] + red[(16+jl*4+1)*128+b] + red[(32+jl*4+1)*128+b] + e.y;
            float gg = a1[jl*4+2] + red[(jl*4+2)*128+b] + red[(16+jl*4+2)*128+b] + red[(32+jl*4+2)*128+b] + e.z;
            float go = a1[jl*4+3] + red[(jl*4+3)*128+b] + red[(16+jl*4+3)*128+b] + red[(32+jl*4+3)*128+b] + e.w;
            float ce = cep[jl];
            float cv = sigm(gf)*ce + sigm(gi)*tanhf(gg);
            cn[jl] = cv;
            hn[jl] = sigm(go)*tanhf(cv);
        }
        reinterpret_cast<float4*>(csT)[g4]  = ce4;                                 // committed thru t-1
        reinterpret_cast<float4*>(c1T)[g4]  = make_float4(cn[0],cn[1],cn[2],cn[3]); // tentative t
        reinterpret_cast<float4*>(hswT)[g4] = he4;
        reinterpret_cast<float4*>(h1wT)[g4] = make_float4(hn[0],hn[1],hn[2],hn[3]);
        if (bid == 0){
            if (t > 0) out_emit[(size_t)b*TT + (t-1)] = mask ? 0.f : (float)kprev;
            label[b] = sel;   // idempotent-select race-safe
        }
    }
}

// ---- B: joint = relu(h1@WpredT + b_pred + encprojT[t]) ; reset slots ----
__global__ __launch_bounds__(512) void kB(
    const float* __restrict__ WpredT, const float* __restrict__ encprojT,
    const float* __restrict__ b_pred, const float* __restrict__ h1T,
    float* __restrict__ jointT, unsigned long long* __restrict__ slot8, int t)
{
    __shared__ float lw[HH*4];        // 10.2 KB
    __shared__ float red[3*4*128];    // 6.1 KB
    const int bid = xcd_tile(blockIdx.x, 20);   // 160 blocks, 4 n each
    const int tid = threadIdx.x;
    const int b = tid & 127, kh = tid >> 7;
    const int n0 = bid*4;
    for (int i=tid; i<HH*4; i+=512)
        lw[i] = WpredT[(size_t)(i>>2)*HH + n0 + (i&3)];
    if (bid == 0 && kh == 3){   // reset slots (A consumed them; C refills them)
        #pragma unroll
        for (int q=0;q<8;++q) slot8[q*128 + b] = 0ULL;
    }
    __syncthreads();
    const float4* hp = reinterpret_cast<const float4*>(h1T);
    float a[4] = {0.f,0.f,0.f,0.f};
    const int k0 = kh*40;
    #pragma unroll 2
    for (int k4=k0; k4<k0+40; ++k4){
        float4 hv = hp[(size_t)k4*BB + b];
        #pragma unroll
        for (int q=0;q<4;++q){
            float h = (q==0)?hv.x:(q==1)?hv.y:(q==2)?hv.z:hv.w;
            f32x4v w = *reinterpret_cast<const f32x4v*>(&lw[(k4*4+q)*4]);
            #pragma unroll
            for (int ee=0; ee<4; ++ee) a[ee] = fmaf(w[ee], h, a[ee]);
        }
    }
    if (kh > 0){
        #pragma unroll
        for (int u=0;u<4;++u) red[((kh-1)*4+u)*128 + b] = a[u];
    }
    __syncthreads();
    if (kh == 0){
        float jn[4];
        #pragma unroll
        for (int u=0;u<4;++u){
            float s = a[u] + red[u*128+b] + red[(4+u)*128+b] + red[(8+u)*128+b]
                    + b_pred[n0+u] + encprojT[((size_t)t*HH + n0+u)*BB + b];
            jn[u] = fmaxf(s, 0.f);
        }
        reinterpret_cast<float4*>(jointT)[(size_t)bid*BB + b] =
            make_float4(jn[0],jn[1],jn[2],jn[3]);
    }
}

// ---- C: logits + argmax ----
__global__ __launch_bounds__(512) void kC(
    const float* __restrict__ WoutT3, const float* __restrict__ boutP3,
    const float* __restrict__ jointT, unsigned long long* __restrict__ slot8)
{
    __shared__ float lw[HH*20];        // rows of 20 (19 used), 51.2 KB
    __shared__ float red[3*19*128];    // 29.2 KB
    const int bid = xcd_tile(blockIdx.x, 27);   // 216 blocks, 19 v each
    const int tid = threadIdx.x;
    const int b = tid & 127, kh = tid >> 7;
    const int v0 = bid*19;
    for (int i=tid; i<HH*19; i+=512){
        int k = i/19, u = i - k*19;
        lw[k*20 + u] = WoutT3[(size_t)k*VP3 + v0 + u];
    }
    __syncthreads();
    const float4* jp = reinterpret_cast<const float4*>(jointT);
    float a[19];
    #pragma unroll
    for (int u=0;u<19;++u) a[u]=0.f;
    const int k0 = kh*40;
    #pragma unroll 2
    for (int k4=k0; k4<k0+40; ++k4){
        float4 jv = jp[(size_t)k4*BB + b];
        #pragma unroll
        for (int q=0;q<4;++q){
            float h = (q==0)?jv.x:(q==1)?jv.y:(q==2)?jv.z:jv.w;
            const f32x4v* wr = reinterpret_cast<const f32x4v*>(&lw[(k4*4+q)*20]);
            #pragma unroll
            for (int g=0; g<4; ++g){
                f32x4v w = wr[g];
                #pragma unroll
                for (int ee=0; ee<4; ++ee) a[g*4+ee] = fmaf(w[ee], h, a[g*4+ee]);
            }
            f32x4v w4 = wr[4];            // elements 16..18 valid, 19 = pad (unused)
            a[16] = fmaf(w4[0], h, a[16]);
            a[17] = fmaf(w4[1], h, a[17]);
            a[18] = fmaf(w4[2], h, a[18]);
        }
    }
    if (kh > 0){
        #pragma unroll
        for (int u=0;u<19;++u) red[((kh-1)*19+u)*128 + b] = a[u];
    }
    __syncthreads();
    if (kh == 0){
        unsigned long long key = 0ULL;
        #pragma unroll
        for (int u=0;u<19;++u){
            float s = a[u] + red[u*128+b] + red[(19+u)*128+b] + red[(38+u)*128+b] + boutP3[v0+u];
            unsigned long long kk = packkey(s, (unsigned)(v0+u));
            if (kk > key) key = kk;
        }
        atomicMax(&slot8[(bid&7)*128 + b], key);
    }
}

// ---- final: emit t=511, hF, cF ----
__global__ __launch_bounds__(256) void kFin(const int* __restrict__ lens,
                        const unsigned long long* __restrict__ slot8,
                        const float* __restrict__ hsT, const float* __restrict__ h1T,
                        const float* __restrict__ csT, const float* __restrict__ c1T,
                        float* __restrict__ dout)
{
    int i = blockIdx.x*256 + threadIdx.x;
    if (i >= BB*HH) return;
    int b = i / HH, jj = i % HH;
    unsigned long long key = slot8[b];
    #pragma unroll
    for (int q=1;q<8;++q){ unsigned long long o=slot8[q*128+b]; if(o>key)key=o; }
    int k = (int)(~(unsigned)key);
    bool m = ((TT-1) >= lens[b]) || (k == 0);
    size_t o = taddr(jj, b);
    dout[BB*TT + i]         = m ? hsT[o] : h1T[o];
    dout[BB*TT + BB*HH + i] = m ? csT[o] : c1T[o];
    if (i < BB){
        unsigned long long key2 = slot8[i];
        #pragma unroll
        for (int q=1;q<8;++q){ unsigned long long o2=slot8[q*128+i]; if(o2>key2)key2=o2; }
        int k2 = (int)(~(unsigned)key2);
        bool mm = ((TT-1) >= lens[i]) || (k2 == 0);
        dout[(size_t)i*TT + (TT-1)] = mm ? 0.0f : (float)k2;
    }
}

// ================= fallback (small ws): R1 basic kernels =================
__global__ __launch_bounds__(256) void k_init(const float* __restrict__ h0, const float* __restrict__ c0,
                       float* __restrict__ hs0, float* __restrict__ cs,
                       int* __restrict__ label, unsigned long long* __restrict__ slot){
    int i = blockIdx.x*256 + threadIdx.x;
    if (i < BB*HH){ hs0[i] = h0[i]; cs[i] = c0[i]; }
    if (i < BB){ label[i] = 0; slot[i] = 0ULL; }
}

__global__ __launch_bounds__(256) void k_p1o(
    const float* __restrict__ Whh, const float* __restrict__ Wih,
    const float* __restrict__ embedding,
    const float* __restrict__ b_ih, const float* __restrict__ b_hh,
    const int* __restrict__ lens,
    const float* __restrict__ hs_r, float* __restrict__ hs_w,
    const float* __restrict__ h1_r, float* __restrict__ h1_w,
    float* c_state, float* c1, int* label,
    const unsigned long long* __restrict__ slot,
    float* __restrict__ out_emit, int t)
{
    int tile = (blockIdx.x & 7)*20 + (blockIdx.x >> 3);
    int jt = tile >> 4, bg = tile & 15;
    int lane = threadIdx.x & 63, w = threadIdx.x >> 6;
    int j = (jt<<6) + lane, b0 = bg<<3;

    bool mask[8]; int kprev[8]; int sel[8];
    #pragma unroll
    for (int bi=0; bi<8; ++bi){
        int b = b0+bi;
        if (t == 0){ mask[bi]=true; sel[bi]=0; kprev[bi]=0; }
        else {
            unsigned long long key = slot[b];
            int k = (int)(~(unsigned)key);
            int lab = label[b];
            bool m = ((t-1) >= lens[b]) || (k == 0);
            mask[bi]=m; kprev[bi]=k; sel[bi] = m ? lab : k;
        }
    }
    float acc[8];
    #pragma unroll
    for (int i=0;i<8;i++) acc[i]=0.f;
    const float* wrow  = Whh + (size_t)(w*HH + j)*HH;
    const float* wrow2 = Wih + (size_t)(w*HH + j)*HH;
    for (int kc=0; kc<HH; kc+=16){
        float wv[16], wv2[16];
        #pragma unroll
        for (int q=0;q<4;q++){
            float4 f = *reinterpret_cast<const float4*>(wrow + kc + q*4);
            wv[q*4+0]=f.x; wv[q*4+1]=f.y; wv[q*4+2]=f.z; wv[q*4+3]=f.w;
            float4 f2 = *reinterpret_cast<const float4*>(wrow2 + kc + q*4);
            wv2[q*4+0]=f2.x; wv2[q*4+1]=f2.y; wv2[q*4+2]=f2.z; wv2[q*4+3]=f2.w;
        }
        #pragma unroll
        for (int bi=0; bi<8; ++bi){
            int b = b0+bi;
            const float* hp0 = hs_r + (size_t)b*HH + kc;
            const float* hp1 = h1_r + (size_t)b*HH + kc;
            float a = acc[bi];
            if (mask[bi]){
                #pragma unroll
                for (int k=0;k<16;k++) a = fmaf(hp0[k], wv[k], a);
            } else {
                #pragma unroll
                for (int k=0;k<16;k++) a = fmaf(hp1[k], wv[k], a);
            }
            if (t > 0){
                const float* ep = embedding + (size_t)sel[bi]*HH + kc;
                #pragma unroll
                for (int k=0;k<16;k++) a = fmaf(ep[k], wv2[k], a);
            }
            acc[bi] = a;
        }
    }
    __shared__ float xch[8][4][64];
    #pragma unroll
    for (int bi=0; bi<8; ++bi)
        xch[bi][w][lane] = acc[bi] + b_ih[w*HH + j] + b_hh[w*HH + j];
    __syncthreads();
    #pragma unroll
    for (int r=0; r<2; ++r){
        int bi = (w<<1) + r;
        int b  = b0 + bi;
        size_t o = (size_t)b*HH + j;
        float gi = xch[bi][0][lane], gf = xch[bi][1][lane];
        float gg = xch[bi][2][lane], go = xch[bi][3][lane];
        float ce = mask[bi] ? c_state[o] : c1[o];
        float c2 = sigm(gf)*ce + sigm(gi)*tanhf(gg);
        float h2 = sigm(go)*tanhf(c2);
        float he = mask[bi] ? hs_r[o] : h1_r[o];
        c_state[o] = ce; c1[o] = c2; hs_w[o] = he; h1_w[o] = h2;
    }
    if (jt == 0 && t > 0 && threadIdx.x < 8){
        int bi = threadIdx.x; int b = b0 + bi;
        out_emit[(size_t)b*TT + (t-1)] = mask[bi] ? 0.0f : (float)kprev[bi];
        label[b] = sel[bi];
    }
}

__global__ __launch_bounds__(128) void k_p2o(
    const float* __restrict__ Wpred, const float* __restrict__ Wenc,
    const float* __restrict__ x, const float* __restrict__ b_enc,
    const float* __restrict__ b_pred, const float* __restrict__ h1,
    float* __restrict__ joint, unsigned long long* __restrict__ slot, int t)
{
    int tile = (blockIdx.x & 7)*20 + (blockIdx.x >> 3);
    int nt = tile / 32, bg = tile % 32;
    int lane = threadIdx.x & 63, w = threadIdx.x >> 6;
    int n = nt*128 + w*64 + lane, b0 = bg*4;
    float acc[4] = {0.f,0.f,0.f,0.f};
    const float* wr  = Wpred + (size_t)n*HH;
    const float* wr2 = Wenc  + (size_t)n*HH;
    for (int kc=0; kc<HH; kc+=16){
        float wv[16], wv2[16];
        #pragma unroll
        for (int q=0;q<4;q++){
            float4 f = *reinterpret_cast<const float4*>(wr + kc + q*4);
            wv[q*4+0]=f.x; wv[q*4+1]=f.y; wv[q*4+2]=f.z; wv[q*4+3]=f.w;
            float4 f2 = *reinterpret_cast<const float4*>(wr2 + kc + q*4);
            wv2[q*4+0]=f2.x; wv2[q*4+1]=f2.y; wv2[q*4+2]=f2.z; wv2[q*4+3]=f2.w;
        }
        #pragma unroll
        for (int bi=0; bi<4; ++bi){
            int b = b0+bi;
            const float* hp = h1 + (size_t)b*HH + kc;
            float a = acc[bi];
            #pragma unroll
            for (int k=0;k<16;k++) a = fmaf(hp[k], wv[k], a);
            const float* xp = x + (size_t)b*HH*TT + (size_t)kc*TT + t;
            #pragma unroll
            for (int k=0;k<16;k++) a = fmaf(xp[(size_t)k*TT], wv2[k], a);
            acc[bi] = a;
        }
    }
    #pragma unroll
    for (int bi=0; bi<4; ++bi){
        int b = b0+bi;
        joint[(size_t)b*HH + n] = fmaxf(acc[bi] + b_pred[n] + b_enc[n], 0.0f);
    }
    if (tile == 0) slot[threadIdx.x] = 0ULL;
}

__global__ __launch_bounds__(256) void k_p3o(
    const float* __restrict__ Wout, const float* __restrict__ b_out,
    const float* __restrict__ joint, unsigned long long* __restrict__ slot)
{
    int tile = (blockIdx.x & 7)*34 + (blockIdx.x >> 3);
    int vt = tile >> 4, bg = tile & 15;
    int lane = threadIdx.x & 63, w = threadIdx.x >> 6;
    int v = vt*256 + w*64 + lane;
    bool valid = v < VV;
    int vv = valid ? v : (VV-1);
    int b0 = bg*8;
    float acc[8];
    #pragma unroll
    for (int i=0;i<8;i++) acc[i]=0.f;
    const float* wr = Wout + (size_t)vv*HH;
    for (int kc=0; kc<HH; kc+=16){
        float wv[16];
        #pragma unroll
        for (int q=0;q<4;q++){
            float4 f = *reinterpret_cast<const float4*>(wr + kc + q*4);
            wv[q*4+0]=f.x; wv[q*4+1]=f.y; wv[q*4+2]=f.z; wv[q*4+3]=f.w;
        }
        #pragma unroll
        for (int bi=0; bi<8; ++bi){
            int b = b0+bi;
            const float* jp = joint + (size_t)b*HH + kc;
            float a = acc[bi];
            #pragma unroll
            for (int k=0;k<16;k++) a = fmaf(jp[k], wv[k], a);
            acc[bi] = a;
        }
    }
    float bofl = b_out[vv];
    __shared__ unsigned long long redo[4][8];
    #pragma unroll
    for (int bi=0; bi<8; ++bi){
        unsigned long long key = valid ? packkey(acc[bi] + bofl, (unsigned)v) : 0ULL;
        #pragma unroll
        for (int off=32; off>0; off>>=1){
            unsigned long long o = __shfl_xor(key, off, 64);
            if (o > key) key = o;
        }
        if (lane == 0) redo[w][bi] = key;
    }
    __syncthreads();
    if (threadIdx.x < 8){
        int bi = threadIdx.x;
        unsigned long long m = redo[0][bi];
        #pragma unroll
        for (int q=1;q<4;q++) if (redo[q][bi] > m) m = redo[q][bi];
        atomicMax(&slot[b0+bi], m);
    }
}

__global__ __launch_bounds__(256) void k_finalo(const int* __restrict__ lens,
                        const unsigned long long* __restrict__ slot,
                        const float* __restrict__ hs_r, const float* __restrict__ h1_r,
                        const float* __restrict__ cs,  const float* __restrict__ c1,
                        float* __restrict__ dout)
{
    int i = blockIdx.x*256 + threadIdx.x;
    if (i >= BB*HH) return;
    int b = i / HH;
    unsigned long long key = slot[b];
    int k = (int)(~(unsigned)key);
    bool m = ((TT-1) >= lens[b]) || (k == 0);
    dout[BB*TT + i]         = m ? hs_r[i] : h1_r[i];
    dout[BB*TT + BB*HH + i] = m ? cs[i]   : c1[i];
    if (i < BB){
        unsigned long long key2 = slot[i];
        int k2 = (int)(~(unsigned)key2);
        bool mm = ((TT-1) >= lens[i]) || (k2 == 0);
        dout[(size_t)i*TT + (TT-1)] = mm ? 0.0f : (float)k2;
    }
}

extern "C" void kernel_launch(void* const* d_in, const int* in_sizes, int n_in,
                              void* d_out, int out_size, void* d_ws, size_t ws_size,
                              hipStream_t stream)
{
    const float* x     = (const float*)d_in[0];
    const int*   lens  = (const int*)  d_in[1];
    const float* emb   = (const float*)d_in[2];
    const float* Wih   = (const float*)d_in[3];
    const float* Whh   = (const float*)d_in[4];
    const float* bih   = (const float*)d_in[5];
    const float* bhh   = (const float*)d_in[6];
    const float* Wenc  = (const float*)d_in[7];
    const float* benc  = (const float*)d_in[8];
    const float* Wpred = (const float*)d_in[9];
    const float* bpred = (const float*)d_in[10];
    const float* Wout  = (const float*)d_in[11];
    const float* bout  = (const float*)d_in[12];
    const float* h0    = (const float*)d_in[13];
    const float* c0    = (const float*)d_in[14];
    float* out = (float*)d_out;
    (void)in_sizes; (void)n_in; (void)out_size;

    char* ws = (char*)d_ws;
    size_t off = 0;
    auto alloc = [&](size_t bytes) -> void* {
        void* p = ws + off; off += (bytes + 255) & ~(size_t)255; return p;
    };
    auto aligned = [](size_t bytes){ return (bytes + 255) & ~(size_t)255; };

    const size_t BH = (size_t)BB*HH*sizeof(float);
    float* hs0  = (float*)alloc(BH);
    float* hs1  = (float*)alloc(BH);
    float* h1b0 = (float*)alloc(BH);
    float* h1b1 = (float*)alloc(BH);
    float* cs   = (float*)alloc(BH);
    float* c1   = (float*)alloc(BH);
    float* joint= (float*)alloc(BH);
    int* label  = (int*)alloc(BB*sizeof(int));
    unsigned long long* slot8 = (unsigned long long*)alloc(8*BB*sizeof(unsigned long long));

    size_t need = off
        + aligned((size_t)HH*G4*sizeof(float))      // WhhT
        + aligned((size_t)HH*G4*sizeof(float))      // WihT
        + aligned((size_t)HH*HH*sizeof(float))      // WpredT
        + aligned((size_t)HH*HH*sizeof(float))      // WencT
        + aligned((size_t)HH*VP3*sizeof(float))     // WoutT3
        + aligned((size_t)VP3*sizeof(float))        // boutP3
        + aligned((size_t)HH*VE*sizeof(float))      // embT
        + aligned((size_t)(VV+1)*G4*sizeof(float))  // embproj
        + aligned((size_t)TT*BB*HH*sizeof(float));  // encprojT

    if (ws_size >= need){
        float* WhhT   = (float*)alloc((size_t)HH*G4*sizeof(float));
        float* WihT   = (float*)alloc((size_t)HH*G4*sizeof(float));
        float* WpredT = (float*)alloc((size_t)HH*HH*sizeof(float));
        float* WencT  = (float*)alloc((size_t)HH*HH*sizeof(float));
        float* WoutT3 = (float*)alloc((size_t)HH*VP3*sizeof(float));
        float* boutP3 = (float*)alloc((size_t)VP3*sizeof(float));
        float* embT   = (float*)alloc((size_t)HH*VE*sizeof(float));
        float* embproj= (float*)alloc((size_t)(VV+1)*G4*sizeof(float));
        float* encprojT=(float*)alloc((size_t)TT*BB*HH*sizeof(float));

        k_init3<<<(BB*HH+255)/256, 256, 0, stream>>>(h0, c0, hs0, cs, label, slot8);
        k_tr_gate<<<(G4*160+255)/256, 256, 0, stream>>>(Whh, WhhT);
        k_tr_gate<<<(G4*160+255)/256, 256, 0, stream>>>(Wih, WihT);
        k_tr640 <<<(HH*160+255)/256, 256, 0, stream>>>(Wpred, WpredT);
        k_tr640 <<<(HH*160+255)/256, 256, 0, stream>>>(Wenc,  WencT);
        k_tr_wout3<<<(VP3*160+255)/256, 256, 0, stream>>>(Wout, WoutT3);
        k_boutpad3<<<(VP3+255)/256, 256, 0, stream>>>(bout, boutP3);
        k_tr_embT<<<(160*VE+255)/256, 256, 0, stream>>>(emb, embT);
        k_embproj3<<<17*160, 256, 0, stream>>>(embT, WihT, bih, bhh, embproj);
        k_encprojT2<<<20480, 128, 0, stream>>>(x, WencT, benc, encprojT);

        float* hsbuf[2] = {hs0, hs1};
        float* h1buf[2] = {h1b0, h1b1};
        for (int t = 0; t < TT; ++t){
            const float* hsr = hsbuf[t & 1];
            float*       hsw = hsbuf[(t+1) & 1];
            const float* h1r = h1buf[(t+1) & 1];
            float*       h1w = h1buf[t & 1];
            kA<<<160, 512, 0, stream>>>(WhhT, embproj, lens, hsr, hsw, h1r, h1w,
                                        cs, c1, label, slot8, out, t);
            kB<<<160, 512, 0, stream>>>(WpredT, encprojT, bpred, h1w, joint, slot8, t);
            kC<<<216, 512, 0, stream>>>(WoutT3, boutP3, joint, slot8);
        }
        kFin<<<(BB*HH+255)/256, 256, 0, stream>>>(lens, slot8, hsbuf[0], h1buf[1], cs, c1, out);
        return;
    }

    // -------- fallback: basic per-step path (small ws) --------
    unsigned long long* slot = slot8;
    k_init<<<(BB*HH+255)/256, 256, 0, stream>>>(h0, c0, hs0, cs, label, slot);
    float* hsbuf[2] = {hs0, hs1};
    float* h1buf[2] = {h1b0, h1b1};
    for (int t = 0; t < TT; ++t){
        const float* hsr = hsbuf[t & 1];
        float*       hsw = hsbuf[(t+1) & 1];
        const float* h1r = h1buf[(t+1) & 1];
        float*       h1w = h1buf[t & 1];
        k_p1o<<<160, 256, 0, stream>>>(Whh, Wih, emb, bih, bhh, lens,
                                       hsr, hsw, h1r, h1w, cs, c1, label, slot, out, t);
        k_p2o<<<160, 128, 0, stream>>>(Wpred, Wenc, x, benc, bpred, h1w, joint, slot, t);
        k_p3o<<<272, 256, 0, stream>>>(Wout, bout, joint, slot);
    }
    k_finalo<<<(BB*HH+255)/256, 256, 0, stream>>>(lens, slot, hsbuf[0], h1buf[1], cs, c1, out);
}